// Round 1
// baseline (250.856 us; speedup 1.0000x reference)
//
#include <hip/hip_runtime.h>
#include <hip/hip_bf16.h>
#include <stdint.h>

#define N_BATCH 16384
#define D_IN    2048
#define E_OUT   512
#define K_CONV  1537   // D_IN - E_OUT + 1
#define EPS_N   1e-12f
#define BKD     64     // K-depth per iteration
#define N_ITERS 26     // 1664 / BKD (band-limited K range, uniform for all blocks)

typedef unsigned short u16;
typedef __bf16 bf16x8 __attribute__((ext_vector_type(8)));
typedef float  f32x4  __attribute__((ext_vector_type(4)));

__device__ __forceinline__ unsigned f2bf_sw(float f) {
    union { float f; unsigned int u; } a; a.f = f;
    unsigned int r = a.u + 0x7FFFu + ((a.u >> 16) & 1u);   // RNE
    return r >> 16;
}

__device__ __forceinline__ unsigned pk_bf16(float a, float b) {
#if __has_builtin(__builtin_amdgcn_cvt_pk_bf16_f32)
    typedef __bf16 bf16x2 __attribute__((ext_vector_type(2)));
    bf16x2 r = __builtin_amdgcn_cvt_pk_bf16_f32(a, b);     // HW RNE, 1 inst / 2 elems
    union { bf16x2 v; unsigned u; } c; c.v = r;
    return c.u;
#else
    return f2bf_sw(a) | (f2bf_sw(b) << 16);
#endif
}

// ---------------- densify banded W into bf16 (E_OUT x D_IN) ----------------
__global__ __launch_bounds__(256) void prep_w_kernel(const float* __restrict__ w,
                                                     u16* __restrict__ wb) {
    int idx = blockIdx.x * 256 + threadIdx.x;
    int e = idx >> 11;
    int d = idx & (D_IN - 1);
    int k = d - e;
    float v = (k >= 0 && k < K_CONV) ? w[e * K_CONV + k] : 0.0f;
    wb[idx] = (u16)f2bf_sw(v);
}

// ---------------- fused cvt + bf16 MFMA GEMM + bias + row-ssq ----------------
// Same double-buffered one-barrier pipeline as the 275.6us version, but with a
// COALESCED staging map: chunk li -> (row = li>>3, oct = li&7) so each wave-load
// covers 8 rows x 128B contiguous runs (16 fully-used lines/instr) instead of a
// 64-row column at 8KB inter-lane stride (64 lines/instr). LDS tiles become
// row-major [128][64] u16 with XOR chunk swizzle (oct ^= row&7) to keep the
// ds_read_b128 fragment reads bank-conflict-free: swizzle applied at ds_write
// for A (reg-staged) and via pre-swizzled global source octet for B (glds needs
// a lane-linear LDS dest; the permutation stays inside each row's contiguous
// 128B segment so coalescing is preserved). MFMA operand contents bit-identical.
__global__ __launch_bounds__(256, 2) void gemm_fused_kernel(const float* __restrict__ A,
                                                            const u16* __restrict__ B,
                                                            const float* __restrict__ bias,
                                                            float* __restrict__ C,
                                                            float* __restrict__ Psq) {
    __shared__ __align__(16) u16 As[2][128][64];   // 2 x 16 KB, row-major + swizzle
    __shared__ __align__(16) u16 Bs[2][128][64];   // 2 x 16 KB
    __shared__ float ssq_lds[128];

    const int tid  = threadIdx.x;
    const int lane = tid & 63;
    const int wave = tid >> 6;
    const int quad = lane >> 4;
    const int r16  = lane & 15;
    const int wm   = (wave >> 1) << 6;
    const int wn   = (wave & 1) << 6;

    // XCD-aware decode: 4 n-tiles of one m-row adjacent on one XCD (L%8 = xcd)
    const int L     = blockIdx.x;        // [0, 512)
    const int xcd   = L & 7;
    const int s     = L >> 3;            // [0, 64)
    const int n_idx = s & 3;
    const int m_idx = (s >> 2) * 8 + xcd;

    const int m0 = m_idx * 128;
    const int n0 = n_idx * 128;
    const int k_begin = n0;              // band-limited K: [n0, n0+1664)

    // staging map: 1024 16B-chunks per matrix per tile, 4 per thread
    // chunk li: row = li>>3 (tile row), oct = li&7 (16B k-octet within row)
    const float* agN[4];                 // next A tile to PREFETCH (reg loads)
    const u16*   bgN[4];                 // next B tile to stage (glds)
    u16* asP[2][4];
    u16* bsP[2][4];
#pragma unroll
    for (int c = 0; c < 4; ++c) {
        const int li  = tid + 256 * c;
        const int row = li >> 3;         // [0, 128)
        const int oct = li & 7;          // [0, 8)
        const int sw  = oct ^ (row & 7); // swizzled octet slot
        // A source: linear octet (swizzle applied at the ds_write instead)
        agN[c] = A + (size_t)(m0 + row) * D_IN + k_begin + oct * 8;
        // B source: pre-swizzled octet (glds dest must stay lane-linear)
        bgN[c] = B + (size_t)(n0 + row) * D_IN + k_begin + sw * 8;
        asP[0][c] = &As[0][0][0] + (row * 8 + sw) * 8;   // swizzled slot
        asP[1][c] = &As[1][0][0] + (row * 8 + sw) * 8;
        bsP[0][c] = &Bs[0][0][0] + li * 8;               // lane-linear
        bsP[1][c] = &Bs[1][0][0] + li * 8;
    }

    // fragment read bases (swizzled), kk = 0/1; +t4*1024 walks rows, +8192 = buf1
    const int sq = r16 & 7;
    const u16* aF[2];
    const u16* bF[2];
    aF[0] = &As[0][wm + r16][((quad    ) ^ sq) * 8];
    aF[1] = &As[0][wm + r16][((quad + 4) ^ sq) * 8];
    bF[0] = &Bs[0][wn + r16][((quad    ) ^ sq) * 8];
    bF[1] = &Bs[0][wn + r16][((quad + 4) ^ sq) * 8];

    f32x4 acc[4][4] = {};
    f32x4 arE[8], arO[8];                // A reg slots: tile parity even / odd

#define LOAD_A(dst, off)                                        \
    _Pragma("unroll")                                           \
    for (int c = 0; c < 4; ++c) {                               \
        dst[2*c]   = *(const f32x4*)(agN[c] + (off));           \
        dst[2*c+1] = *(const f32x4*)(agN[c] + (off) + 4);       \
    }

#define PACK_A(src, buf)                                        \
    _Pragma("unroll")                                           \
    for (int c = 0; c < 4; ++c) {                               \
        uint4 o;                                                \
        o.x = pk_bf16(src[2*c][0],   src[2*c][1]);              \
        o.y = pk_bf16(src[2*c][2],   src[2*c][3]);              \
        o.z = pk_bf16(src[2*c+1][0], src[2*c+1][1]);            \
        o.w = pk_bf16(src[2*c+1][2], src[2*c+1][3]);            \
        *(uint4*)asP[buf][c] = o;                               \
    }

#define GLDS_B(buf)                                             \
    _Pragma("unroll")                                           \
    for (int c = 0; c < 4; ++c)                                 \
        __builtin_amdgcn_global_load_lds(                       \
            (const __attribute__((address_space(1))) void*)bgN[c], \
            (__attribute__((address_space(3))) void*)bsP[buf][c], 16, 0, 0);

#define COMPUTE(buf)                                            \
    _Pragma("unroll")                                           \
    for (int kk = 0; kk < 2; ++kk) {                            \
        bf16x8 af[4], bf[4];                                    \
        _Pragma("unroll")                                       \
        for (int t4 = 0; t4 < 4; ++t4)                          \
            af[t4] = *(const bf16x8*)(aF[kk] + (buf) * 8192 + t4 * 1024); \
        _Pragma("unroll")                                       \
        for (int t4 = 0; t4 < 4; ++t4)                          \
            bf[t4] = *(const bf16x8*)(bF[kk] + (buf) * 8192 + t4 * 1024); \
        _Pragma("unroll")                                       \
        for (int i = 0; i < 4; ++i)                             \
            _Pragma("unroll")                                   \
            for (int j = 0; j < 4; ++j)                         \
                acc[i][j] = __builtin_amdgcn_mfma_f32_16x16x32_bf16(af[i], bf[j], acc[i][j], 0, 0, 0); \
    }

    // ---- prologue: tile0 sync-staged to buf0; tile1 regs prefetched ----
    {
        f32x4 arT[8];
        LOAD_A(arT, 0);                  // tile 0
        LOAD_A(arO, BKD);                // tile 1 (odd slot) — in flight
        GLDS_B(0);                       // B tile 0 -> buf0
#pragma unroll
        for (int c = 0; c < 4; ++c) bgN[c] += BKD;     // -> tile 1
#pragma unroll
        for (int c = 0; c < 4; ++c) agN[c] += 2 * BKD; // -> tile 2
        PACK_A(arT, 0);                  // waits only on arT
        __syncthreads();                 // drains glds(0) + arO loads + ds_writes
    }

    // ---- main loop: 13 double-iterations, one barrier per iteration ----
    for (int p = 0; p < 13; ++p) {
        // even iter: it = 2p; compute buf0, stage tile it+1 -> buf1
        {
            const int it = 2 * p;
            if (it + 1 < N_ITERS) {
                GLDS_B(1);
#pragma unroll
                for (int c = 0; c < 4; ++c) bgN[c] += BKD;
                if (it + 2 < N_ITERS) {
                    LOAD_A(arE, 0);      // tile it+2 (even slot)
#pragma unroll
                    for (int c = 0; c < 4; ++c) agN[c] += BKD;
                }
                PACK_A(arO, 1);          // tile it+1 — regs complete (prev barrier)
            }
            COMPUTE(0);
            __syncthreads();
        }
        // odd iter: it = 2p+1; compute buf1, stage tile it+1 -> buf0
        {
            const int it = 2 * p + 1;
            if (it + 1 < N_ITERS) {
                GLDS_B(0);
#pragma unroll
                for (int c = 0; c < 4; ++c) bgN[c] += BKD;
                if (it + 2 < N_ITERS) {
                    LOAD_A(arO, 0);      // tile it+2 (odd slot)
#pragma unroll
                    for (int c = 0; c < 4; ++c) agN[c] += BKD;
                }
                PACK_A(arE, 0);          // tile it+1
            }
            COMPUTE(1);
            __syncthreads();
        }
    }

    // ---- epilogue: bias add, store pre-norm C, per-row sum-of-squares ----
    if (tid < 128) ssq_lds[tid] = 0.0f;

    float ssq_t[16];
#pragma unroll
    for (int t = 0; t < 16; ++t) ssq_t[t] = 0.0f;

#pragma unroll
    for (int j = 0; j < 4; ++j) {
        const int col = n0 + wn + j * 16 + r16;
        const float bv = bias[col];
#pragma unroll
        for (int i = 0; i < 4; ++i) {
            const int rowb = m0 + wm + i * 16 + quad * 4;
#pragma unroll
            for (int rg = 0; rg < 4; ++rg) {
                const float v = acc[i][j][rg] + bv;
                C[(size_t)(rowb + rg) * E_OUT + col] = v;
                ssq_t[i * 4 + rg] += v * v;
            }
        }
    }

#pragma unroll
    for (int off = 1; off <= 8; off <<= 1)
#pragma unroll
        for (int t = 0; t < 16; ++t)
            ssq_t[t] += __shfl_xor(ssq_t[t], off, 64);

    __syncthreads();
    if (r16 == 0) {
#pragma unroll
        for (int i = 0; i < 4; ++i)
#pragma unroll
            for (int rg = 0; rg < 4; ++rg)
                atomicAdd(&ssq_lds[wm + i * 16 + quad * 4 + rg], ssq_t[i * 4 + rg]);
    }
    __syncthreads();
    if (tid < 128)
        Psq[(size_t)n_idx * N_BATCH + m0 + tid] = ssq_lds[tid];
}

// ---------------- lite norm: out *= 1/max(sqrt(sum Psq), eps) ----------------
__global__ __launch_bounds__(256) void norm_kernel(float* __restrict__ out,
                                                   const float* __restrict__ Psq) {
    const int wave = threadIdx.x >> 6;
    const int lane = threadIdx.x & 63;
    const size_t row = (size_t)blockIdx.x * 4 + wave;
    const float ss = Psq[row] + Psq[N_BATCH + row] +
                     Psq[2 * N_BATCH + row] + Psq[3 * N_BATCH + row];
    const float inv = 1.0f / fmaxf(sqrtf(ss), EPS_N);
    float4* p = (float4*)(out + row * E_OUT);
    float4 v0 = p[lane * 2];
    float4 v1 = p[lane * 2 + 1];
    v0.x *= inv; v0.y *= inv; v0.z *= inv; v0.w *= inv;
    v1.x *= inv; v1.y *= inv; v1.z *= inv; v1.w *= inv;
    p[lane * 2] = v0;
    p[lane * 2 + 1] = v1;
}

// ---------------- fallback: fused naive fp32 (only if ws too small) ----------------
__global__ __launch_bounds__(256) void naive_kernel(const float* __restrict__ x,
                                                    const float* __restrict__ w,
                                                    const float* __restrict__ b,
                                                    float* __restrict__ out) {
    __shared__ float xs[D_IN];
    __shared__ float os[E_OUT];
    __shared__ float red[4];
    const int n = blockIdx.x;
    const float* xr = x + (size_t)n * D_IN;
    for (int i = threadIdx.x; i < D_IN; i += 256) xs[i] = xr[i];
    __syncthreads();
    for (int i = threadIdx.x; i < E_OUT; i += 256) {
        float s = b[i];
        const float* wr = w + (size_t)i * K_CONV;
        for (int k = 0; k < K_CONV; ++k) s += wr[k] * xs[i + k];
        os[i] = s;
    }
    __syncthreads();
    float ss = 0.0f;
    for (int i = threadIdx.x; i < E_OUT; i += 256) ss += os[i] * os[i];
#pragma unroll
    for (int off = 32; off > 0; off >>= 1) ss += __shfl_xor(ss, off, 64);
    if ((threadIdx.x & 63) == 0) red[threadIdx.x >> 6] = ss;
    __syncthreads();
    const float inv = 1.0f / fmaxf(sqrtf(red[0] + red[1] + red[2] + red[3]), EPS_N);
    float* orow = out + (size_t)n * E_OUT;
    for (int i = threadIdx.x; i < E_OUT; i += 256) orow[i] = os[i] * inv;
}

extern "C" void kernel_launch(void* const* d_in, const int* in_sizes, int n_in,
                              void* d_out, int out_size, void* d_ws, size_t ws_size,
                              hipStream_t stream) {
    const float* x = (const float*)d_in[0];
    const float* w = (const float*)d_in[1];
    const float* b = (const float*)d_in[2];
    float* out = (float*)d_out;

    const size_t wb_bytes  = (size_t)E_OUT * D_IN * sizeof(u16);   // 2 MiB
    const size_t psq_bytes = (size_t)4 * N_BATCH * sizeof(float);  // 256 KiB

    if (ws_size < wb_bytes + psq_bytes) {
        naive_kernel<<<N_BATCH, 256, 0, stream>>>(x, w, b, out);
        return;
    }

    u16*   wb  = (u16*)d_ws;
    float* Psq = (float*)((char*)d_ws + wb_bytes);

    prep_w_kernel<<<(E_OUT * D_IN) / 256, 256, 0, stream>>>(w, wb);

    gemm_fused_kernel<<<512, 256, 0, stream>>>(x, wb, b, out, Psq);

    norm_kernel<<<N_BATCH / 4, 256, 0, stream>>>(out, Psq);
}

// Round 2
// 242.993 us; speedup vs baseline: 1.0324x; 1.0324x over previous
//
#include <hip/hip_runtime.h>
#include <hip/hip_bf16.h>
#include <stdint.h>

#define N_BATCH 16384
#define D_IN    2048
#define E_OUT   512
#define K_CONV  1537   // D_IN - E_OUT + 1
#define EPS_N   1e-12f
#define BKD     64     // K-depth per iteration
#define N_ITERS 26     // 1664 / BKD (band-limited K range, uniform for all blocks)

typedef unsigned short u16;
typedef __bf16 bf16x8 __attribute__((ext_vector_type(8)));
typedef float  f32x4  __attribute__((ext_vector_type(4)));

__device__ __forceinline__ unsigned f2bf_sw(float f) {
    union { float f; unsigned int u; } a; a.f = f;
    unsigned int r = a.u + 0x7FFFu + ((a.u >> 16) & 1u);   // RNE
    return r >> 16;
}

__device__ __forceinline__ unsigned pk_bf16(float a, float b) {
#if __has_builtin(__builtin_amdgcn_cvt_pk_bf16_f32)
    typedef __bf16 bf16x2 __attribute__((ext_vector_type(2)));
    bf16x2 r = __builtin_amdgcn_cvt_pk_bf16_f32(a, b);     // HW RNE, 1 inst / 2 elems
    union { bf16x2 v; unsigned u; } c; c.v = r;
    return c.u;
#else
    return f2bf_sw(a) | (f2bf_sw(b) << 16);
#endif
}

// ---------------- densify banded W into bf16 (E_OUT x D_IN) ----------------
__global__ __launch_bounds__(256) void prep_w_kernel(const float* __restrict__ w,
                                                     u16* __restrict__ wb) {
    int idx = blockIdx.x * 256 + threadIdx.x;
    int e = idx >> 11;
    int d = idx & (D_IN - 1);
    int k = d - e;
    float v = (k >= 0 && k < K_CONV) ? w[e * K_CONV + k] : 0.0f;
    wb[idx] = (u16)f2bf_sw(v);
}

// ---------------- fused cvt + bf16 MFMA GEMM + bias + row-ssq ----------------
// Coalesced staging map (row = li>>3, oct = li&7; XOR chunk swizzle oct^row&7)
// verified in the previous round (FETCH_SIZE = 1.0x A bytes, 0 bank conflicts).
// THIS round: replace the per-iteration __syncthreads() (which compiles to a
// full s_waitcnt vmcnt(0) drain of the loads issued in the SAME iteration -->
// full L3/HBM latency exposed every iteration, MfmaUtil 10.7%) with a counted
// s_waitcnt vmcnt(8) + raw s_barrier. Issue order per iter is [4 glds B,
// 8 A-reg loads], so vmcnt(8) drains exactly the B glds while the 8 A loads
// (consumed next iter by PACK, guarded by compiler register-dep waits) stay
// in flight across the barrier. lgkmcnt(0) fences the PACK ds_writes.
__global__ __launch_bounds__(256, 2) void gemm_fused_kernel(const float* __restrict__ A,
                                                            const u16* __restrict__ B,
                                                            const float* __restrict__ bias,
                                                            float* __restrict__ C,
                                                            float* __restrict__ Psq) {
    __shared__ __align__(16) u16 As[2][128][64];   // 2 x 16 KB, row-major + swizzle
    __shared__ __align__(16) u16 Bs[2][128][64];   // 2 x 16 KB
    __shared__ float ssq_lds[128];

    const int tid  = threadIdx.x;
    const int lane = tid & 63;
    const int wave = tid >> 6;
    const int quad = lane >> 4;
    const int r16  = lane & 15;
    const int wm   = (wave >> 1) << 6;
    const int wn   = (wave & 1) << 6;

    // XCD-aware decode: 4 n-tiles of one m-row adjacent on one XCD (L%8 = xcd)
    const int L     = blockIdx.x;        // [0, 512)
    const int xcd   = L & 7;
    const int s     = L >> 3;            // [0, 64)
    const int n_idx = s & 3;
    const int m_idx = (s >> 2) * 8 + xcd;

    const int m0 = m_idx * 128;
    const int n0 = n_idx * 128;
    const int k_begin = n0;              // band-limited K: [n0, n0+1664)

    // staging map: 1024 16B-chunks per matrix per tile, 4 per thread
    // chunk li: row = li>>3 (tile row), oct = li&7 (16B k-octet within row)
    const float* agN[4];                 // next A tile to PREFETCH (reg loads)
    const u16*   bgN[4];                 // next B tile to stage (glds)
    u16* asP[2][4];
    u16* bsP[2][4];
#pragma unroll
    for (int c = 0; c < 4; ++c) {
        const int li  = tid + 256 * c;
        const int row = li >> 3;         // [0, 128)
        const int oct = li & 7;          // [0, 8)
        const int sw  = oct ^ (row & 7); // swizzled octet slot
        // A source: linear octet (swizzle applied at the ds_write instead)
        agN[c] = A + (size_t)(m0 + row) * D_IN + k_begin + oct * 8;
        // B source: pre-swizzled octet (glds dest must stay lane-linear)
        bgN[c] = B + (size_t)(n0 + row) * D_IN + k_begin + sw * 8;
        asP[0][c] = &As[0][0][0] + (row * 8 + sw) * 8;   // swizzled slot
        asP[1][c] = &As[1][0][0] + (row * 8 + sw) * 8;
        bsP[0][c] = &Bs[0][0][0] + li * 8;               // lane-linear
        bsP[1][c] = &Bs[1][0][0] + li * 8;
    }

    // fragment read bases (swizzled), kk = 0/1; +t4*1024 walks rows, +8192 = buf1
    const int sq = r16 & 7;
    const u16* aF[2];
    const u16* bF[2];
    aF[0] = &As[0][wm + r16][((quad    ) ^ sq) * 8];
    aF[1] = &As[0][wm + r16][((quad + 4) ^ sq) * 8];
    bF[0] = &Bs[0][wn + r16][((quad    ) ^ sq) * 8];
    bF[1] = &Bs[0][wn + r16][((quad + 4) ^ sq) * 8];

    f32x4 acc[4][4] = {};
    f32x4 arE[8], arO[8];                // A reg slots: tile parity even / odd

#define LOAD_A(dst, off)                                        \
    _Pragma("unroll")                                           \
    for (int c = 0; c < 4; ++c) {                               \
        dst[2*c]   = *(const f32x4*)(agN[c] + (off));           \
        dst[2*c+1] = *(const f32x4*)(agN[c] + (off) + 4);       \
    }

#define PACK_A(src, buf)                                        \
    _Pragma("unroll")                                           \
    for (int c = 0; c < 4; ++c) {                               \
        uint4 o;                                                \
        o.x = pk_bf16(src[2*c][0],   src[2*c][1]);              \
        o.y = pk_bf16(src[2*c][2],   src[2*c][3]);              \
        o.z = pk_bf16(src[2*c+1][0], src[2*c+1][1]);            \
        o.w = pk_bf16(src[2*c+1][2], src[2*c+1][3]);            \
        *(uint4*)asP[buf][c] = o;                               \
    }

#define GLDS_B(buf)                                             \
    _Pragma("unroll")                                           \
    for (int c = 0; c < 4; ++c)                                 \
        __builtin_amdgcn_global_load_lds(                       \
            (const __attribute__((address_space(1))) void*)bgN[c], \
            (__attribute__((address_space(3))) void*)bsP[buf][c], 16, 0, 0);

#define COMPUTE(buf)                                            \
    _Pragma("unroll")                                           \
    for (int kk = 0; kk < 2; ++kk) {                            \
        bf16x8 af[4], bf[4];                                    \
        _Pragma("unroll")                                       \
        for (int t4 = 0; t4 < 4; ++t4)                          \
            af[t4] = *(const bf16x8*)(aF[kk] + (buf) * 8192 + t4 * 1024); \
        _Pragma("unroll")                                       \
        for (int t4 = 0; t4 < 4; ++t4)                          \
            bf[t4] = *(const bf16x8*)(bF[kk] + (buf) * 8192 + t4 * 1024); \
        _Pragma("unroll")                                       \
        for (int i = 0; i < 4; ++i)                             \
            _Pragma("unroll")                                   \
            for (int j = 0; j < 4; ++j)                         \
                acc[i][j] = __builtin_amdgcn_mfma_f32_16x16x32_bf16(af[i], bf[j], acc[i][j], 0, 0, 0); \
    }

// Counted-vmcnt barrier: drain the 4 B-glds (oldest), keep the 8 A-loads in
// flight; fence own ds_writes with lgkmcnt(0). sched_barrier(0) pins ordering
// (rule #18: compiler may otherwise migrate ops across a raw s_barrier).
#define BAR_FAST()                                              \
    asm volatile("s_waitcnt vmcnt(8) lgkmcnt(0)");              \
    __builtin_amdgcn_sched_barrier(0);                          \
    __builtin_amdgcn_s_barrier();                               \
    __builtin_amdgcn_sched_barrier(0);

    // ---- prologue: tile0 sync-staged to buf0; tile1 regs prefetched ----
    {
        f32x4 arT[8];
        LOAD_A(arT, 0);                  // tile 0
        LOAD_A(arO, BKD);                // tile 1 (odd slot) — in flight
        GLDS_B(0);                       // B tile 0 -> buf0
#pragma unroll
        for (int c = 0; c < 4; ++c) bgN[c] += BKD;     // -> tile 1
#pragma unroll
        for (int c = 0; c < 4; ++c) agN[c] += 2 * BKD; // -> tile 2
        PACK_A(arT, 0);                  // waits only on arT
        __syncthreads();                 // one-time full drain (glds0 + arO + ds_writes)
    }

    // ---- main loop: 12 double-iterations (it = 0..23), full staging, fast barrier ----
    for (int p = 0; p < 12; ++p) {
        // even iter: it = 2p; compute buf0, stage tile it+1 -> buf1, prefetch it+2
        {
            GLDS_B(1);
#pragma unroll
            for (int c = 0; c < 4; ++c) bgN[c] += BKD;
            LOAD_A(arE, 0);              // tile it+2 (even slot)
#pragma unroll
            for (int c = 0; c < 4; ++c) agN[c] += BKD;
            PACK_A(arO, 1);              // tile it+1 — regs complete (compiler dep-wait)
            COMPUTE(0);
            BAR_FAST();
        }
        // odd iter: it = 2p+1; compute buf1, stage tile it+1 -> buf0, prefetch it+2
        {
            GLDS_B(0);
#pragma unroll
            for (int c = 0; c < 4; ++c) bgN[c] += BKD;
            LOAD_A(arO, 0);              // tile it+2 (odd slot)
#pragma unroll
            for (int c = 0; c < 4; ++c) agN[c] += BKD;
            PACK_A(arE, 0);              // tile it+1
            COMPUTE(1);
            BAR_FAST();
        }
    }

    // ---- peeled tail: it = 24 (stage tile 25, no more A prefetch), it = 25 ----
    {
        GLDS_B(1);                       // B tile 25 -> buf1
        PACK_A(arO, 1);                  // A tile 25 (regs loaded at it=23)
        COMPUTE(0);                      // tile 24
        __syncthreads();                 // full drain (tail — correctness first)
        COMPUTE(1);                      // tile 25
    }

    // ---- epilogue: bias add, store pre-norm C, per-row sum-of-squares ----
    __syncthreads();
    if (tid < 128) ssq_lds[tid] = 0.0f;

    float ssq_t[16];
#pragma unroll
    for (int t = 0; t < 16; ++t) ssq_t[t] = 0.0f;

#pragma unroll
    for (int j = 0; j < 4; ++j) {
        const int col = n0 + wn + j * 16 + r16;
        const float bv = bias[col];
#pragma unroll
        for (int i = 0; i < 4; ++i) {
            const int rowb = m0 + wm + i * 16 + quad * 4;
#pragma unroll
            for (int rg = 0; rg < 4; ++rg) {
                const float v = acc[i][j][rg] + bv;
                C[(size_t)(rowb + rg) * E_OUT + col] = v;
                ssq_t[i * 4 + rg] += v * v;
            }
        }
    }

#pragma unroll
    for (int off = 1; off <= 8; off <<= 1)
#pragma unroll
        for (int t = 0; t < 16; ++t)
            ssq_t[t] += __shfl_xor(ssq_t[t], off, 64);

    __syncthreads();
    if (r16 == 0) {
#pragma unroll
        for (int i = 0; i < 4; ++i)
#pragma unroll
            for (int rg = 0; rg < 4; ++rg)
                atomicAdd(&ssq_lds[wm + i * 16 + quad * 4 + rg], ssq_t[i * 4 + rg]);
    }
    __syncthreads();
    if (tid < 128)
        Psq[(size_t)n_idx * N_BATCH + m0 + tid] = ssq_lds[tid];
}

// ---------------- lite norm: out *= 1/max(sqrt(sum Psq), eps) ----------------
__global__ __launch_bounds__(256) void norm_kernel(float* __restrict__ out,
                                                   const float* __restrict__ Psq) {
    const int wave = threadIdx.x >> 6;
    const int lane = threadIdx.x & 63;
    const size_t row = (size_t)blockIdx.x * 4 + wave;
    const float ss = Psq[row] + Psq[N_BATCH + row] +
                     Psq[2 * N_BATCH + row] + Psq[3 * N_BATCH + row];
    const float inv = 1.0f / fmaxf(sqrtf(ss), EPS_N);
    float4* p = (float4*)(out + row * E_OUT);
    float4 v0 = p[lane * 2];
    float4 v1 = p[lane * 2 + 1];
    v0.x *= inv; v0.y *= inv; v0.z *= inv; v0.w *= inv;
    v1.x *= inv; v1.y *= inv; v1.z *= inv; v1.w *= inv;
    p[lane * 2] = v0;
    p[lane * 2 + 1] = v1;
}

// ---------------- fallback: fused naive fp32 (only if ws too small) ----------------
__global__ __launch_bounds__(256) void naive_kernel(const float* __restrict__ x,
                                                    const float* __restrict__ w,
                                                    const float* __restrict__ b,
                                                    float* __restrict__ out) {
    __shared__ float xs[D_IN];
    __shared__ float os[E_OUT];
    __shared__ float red[4];
    const int n = blockIdx.x;
    const float* xr = x + (size_t)n * D_IN;
    for (int i = threadIdx.x; i < D_IN; i += 256) xs[i] = xr[i];
    __syncthreads();
    for (int i = threadIdx.x; i < E_OUT; i += 256) {
        float s = b[i];
        const float* wr = w + (size_t)i * K_CONV;
        for (int k = 0; k < K_CONV; ++k) s += wr[k] * xs[i + k];
        os[i] = s;
    }
    __syncthreads();
    float ss = 0.0f;
    for (int i = threadIdx.x; i < E_OUT; i += 256) ss += os[i] * os[i];
#pragma unroll
    for (int off = 32; off > 0; off >>= 1) ss += __shfl_xor(ss, off, 64);
    if ((threadIdx.x & 63) == 0) red[threadIdx.x >> 6] = ss;
    __syncthreads();
    const float inv = 1.0f / fmaxf(sqrtf(red[0] + red[1] + red[2] + red[3]), EPS_N);
    float* orow = out + (size_t)n * E_OUT;
    for (int i = threadIdx.x; i < E_OUT; i += 256) orow[i] = os[i] * inv;
}

extern "C" void kernel_launch(void* const* d_in, const int* in_sizes, int n_in,
                              void* d_out, int out_size, void* d_ws, size_t ws_size,
                              hipStream_t stream) {
    const float* x = (const float*)d_in[0];
    const float* w = (const float*)d_in[1];
    const float* b = (const float*)d_in[2];
    float* out = (float*)d_out;

    const size_t wb_bytes  = (size_t)E_OUT * D_IN * sizeof(u16);   // 2 MiB
    const size_t psq_bytes = (size_t)4 * N_BATCH * sizeof(float);  // 256 KiB

    if (ws_size < wb_bytes + psq_bytes) {
        naive_kernel<<<N_BATCH, 256, 0, stream>>>(x, w, b, out);
        return;
    }

    u16*   wb  = (u16*)d_ws;
    float* Psq = (float*)((char*)d_ws + wb_bytes);

    prep_w_kernel<<<(E_OUT * D_IN) / 256, 256, 0, stream>>>(w, wb);

    gemm_fused_kernel<<<512, 256, 0, stream>>>(x, wb, b, out, Psq);

    norm_kernel<<<N_BATCH / 4, 256, 0, stream>>>(out, Psq);
}